// Round 16
// baseline (122.756 us; speedup 1.0000x reference)
//
#include <hip/hip_runtime.h>
#include <cstdint>

#define T_TOK 16384
#define H 1024
#define F 256
#define D 3
#define DF 768

typedef unsigned short u16;
typedef __attribute__((ext_vector_type(8))) short short8;
typedef __attribute__((ext_vector_type(4))) float floatx4;

__device__ __forceinline__ u16 f2bf(float f) {
  unsigned u = __float_as_uint(f);
  u += 0x7fff + ((u >> 16) & 1);   // round-to-nearest-even
  return (u16)(u >> 16);
}
__device__ __forceinline__ float bf2f(u16 s) {
  return __uint_as_float(((unsigned)s) << 16);
}

__device__ __forceinline__ void gload_lds16(const void* g, void* l) {
  __builtin_amdgcn_global_load_lds(
      reinterpret_cast<const __attribute__((address_space(1))) void*>(
          reinterpret_cast<uintptr_t>(g)),
      reinterpret_cast<__attribute__((address_space(3))) void*>(
          reinterpret_cast<uintptr_t>(l)),
      16, 0, 0);
}

__device__ __forceinline__ float block_reduce_256(float v, float* red, int tid) {
  #pragma unroll
  for (int o = 32; o > 0; o >>= 1) v += __shfl_xor(v, o);
  __syncthreads();
  if ((tid & 63) == 0) red[tid >> 6] = v;
  __syncthreads();
  return red[0] + red[1] + red[2] + red[3];
}

// -------- fused LN + prep: blocks [0,T_TOK) do LayerNorm+x·gu; blocks
// [T_TOK, T_TOK+DF) do the weight prep (dots + elementwise bf16 convert).
// Independent block families; prep hides under LN's BW-bound time.
__global__ __launch_bounds__(256)
void prep_ln(const float* __restrict__ x, const float* __restrict__ gu,
             const float* __restrict__ W1, const float* __restrict__ lng,
             const float* __restrict__ lnb, const float* __restrict__ b1,
             const float* __restrict__ W2, const float* __restrict__ gv,
             const float* __restrict__ b2, const float* __restrict__ gb,
             u16* __restrict__ xn, float* __restrict__ xu,
             u16* __restrict__ W1p, u16* __restrict__ W2r,
             float* __restrict__ b1p, float* __restrict__ wg,
             float* __restrict__ cg)
{
  const int tid = threadIdx.x;
  if (blockIdx.x < T_TOK) {
    // ---- LayerNorm + gate x-dots ----
    int t = blockIdx.x;
    const float4 xv = *reinterpret_cast<const float4*>(x + (size_t)t * H + tid * 4);
    const float4 g0 = *reinterpret_cast<const float4*>(gu + tid * 4);
    const float4 g1 = *reinterpret_cast<const float4*>(gu + H + tid * 4);
    const float4 g2 = *reinterpret_cast<const float4*>(gu + 2 * H + tid * 4);
    float s  = xv.x + xv.y + xv.z + xv.w;
    float sq = xv.x * xv.x + xv.y * xv.y + xv.z * xv.z + xv.w * xv.w;
    float d0 = xv.x * g0.x + xv.y * g0.y + xv.z * g0.z + xv.w * g0.w;
    float d1 = xv.x * g1.x + xv.y * g1.y + xv.z * g1.z + xv.w * g1.w;
    float d2 = xv.x * g2.x + xv.y * g2.y + xv.z * g2.z + xv.w * g2.w;
    #pragma unroll
    for (int o = 32; o > 0; o >>= 1) {
      s  += __shfl_xor(s, o);  sq += __shfl_xor(sq, o);
      d0 += __shfl_xor(d0, o); d1 += __shfl_xor(d1, o); d2 += __shfl_xor(d2, o);
    }
    __shared__ float red[4][5];
    int w = tid >> 6;
    if ((tid & 63) == 0) {
      red[w][0] = s; red[w][1] = sq; red[w][2] = d0; red[w][3] = d1; red[w][4] = d2;
    }
    __syncthreads();
    float S  = red[0][0] + red[1][0] + red[2][0] + red[3][0];
    float SQ = red[0][1] + red[1][1] + red[2][1] + red[3][1];
    float mu = S * (1.0f / H);
    float var = (SQ - (float)H * mu * mu) * (1.0f / (H - 1));
    float rs = 1.0f / (sqrtf(fmaxf(var, 0.0f)) + 1e-6f);
    ushort4 o4;
    o4.x = f2bf((xv.x - mu) * rs);
    o4.y = f2bf((xv.y - mu) * rs);
    o4.z = f2bf((xv.z - mu) * rs);
    o4.w = f2bf((xv.w - mu) * rs);
    *reinterpret_cast<ushort4*>(xn + (size_t)t * H + tid * 4) = o4;
    if (tid == 0) {
      xu[t]             = red[0][2] + red[1][2] + red[2][2] + red[3][2];
      xu[T_TOK + t]     = red[0][3] + red[1][3] + red[2][3] + red[3][3];
      xu[2 * T_TOK + t] = red[0][4] + red[1][4] + red[2][4] + red[3][4];
    }
  } else {
    // ---- weight prep: one block per (d,f) ----
    __shared__ float red[4];
    int pb = blockIdx.x - T_TOK;     // 0..DF-1
    int d = pb >> 8;
    int f = pb & 255;
    float s1 = 0.f, s2 = 0.f, s3 = 0.f;
    for (int h = tid; h < H; h += 256) {
      float w1v = W1[((size_t)d * F + f) * H + h];
      float gvv = gv[d * H + h];
      s1 += lnb[d * H + h] * w1v;
      s2 += W2[((size_t)d * H + h) * F + f] * gvv;
      if (f == 0) s3 += b2[d * H + h] * gvv;
    }
    float S1 = block_reduce_256(s1, red, tid);
    float S2 = block_reduce_256(s2, red, tid);
    if (tid == 0) {
      b1p[d * F + f] = b1[d * F + f] + S1;
      wg[d * F + f] = S2;
    }
    if (f == 0) {
      float S3 = block_reduce_256(s3, red, tid);
      if (tid == 0) cg[d] = gb[d] + S3;
    }
    // elementwise conversions (grid-stride over prep blocks only)
    int idx = pb * 256 + tid;
    int stride = DF * 256;
    for (int i = idx; i < D * F * H; i += stride) {
      int h = i & (H - 1);
      int dd = i / (F * H);
      W1p[i] = f2bf(W1[i] * lng[dd * H + h]);
    }
    for (int i = idx; i < H * DF; i += stride) {
      int k = i % DF;           // d*F+f
      int hh = i / DF;
      int dd = k >> 8;
      int ff = k & (F - 1);
      W2r[i] = f2bf(W2[((size_t)dd * H + hh) * F + ff]);
    }
  }
}

// ------------- GEMM1 (R16): 64x256xBK32, 4 waves of 64x64 -------------
// BM=64 -> grid 768 = 3 rounds @ 3 blocks/CU (R10 showed this regime is
// worth ~12% vs 1.5 rounds @ 2/CU). acc[4][4]=64 VGPR fits (256,3)'s
// ~170-reg cap with margin (NO acc[4][8] here — that tile spills at any
// 3-waves/EU bound: R8/R11/R14). 4 waves: all share A rows 0..63, wave w
// owns cols w*64..w*64+63. LDS 40KB dbuf (A 4KB + B 16KB per buffer),
// one __syncthreads per K-tile, compiler waits, chunk-XOR swizzle,
// panel dispatch. BN=256 == one domain -> gate fused in-block.
__global__ __launch_bounds__(256, 3)
void gemm_g1(const u16* __restrict__ A, const u16* __restrict__ Bm,
             const float* __restrict__ b1p, const float* __restrict__ wgp,
             const float* __restrict__ xu, const float* __restrict__ cgp,
             u16* __restrict__ o16, float* __restrict__ gateOut)
{
  constexpr int K = 1024, NT = K / 32;
  constexpr int ABUF = 2048;          // A slab u16 (64x32)
  constexpr int BUF = 10240;          // 20KB per buffer
  extern __shared__ u16 LD[];

  const int tid = threadIdx.x, lane = tid & 63, w = tid >> 6;
  const int lr = lane & 15, sl = lane >> 4;

  // panel dispatch: 256 by-tiles = 8 XCDs x 32; 3 bx per by consecutive
  const int bid = blockIdx.x;
  const int xcd = bid & 7, idx = bid >> 3;
  const int by = xcd * 32 + idx / 3;
  const int bx = idx % 3;
  const int m0 = by * 64, n0 = bx * 256;

  const u16* Asrc = A + (size_t)m0 * K;
  const u16* Bsrc = Bm + (size_t)n0 * K;

  // staging: chunk q (16B): row=q>>2, c=q&3; src chunk pre-swizzled
  // sc = c ^ ((row>>1)&3) = (tid&3)^((tid>>3)&3)  (it-invariant: +64 rows)
  const int sc = (tid & 3) ^ ((tid >> 3) & 3);
  // fragment reads: key = (lr>>1)&3 (row = base + lr, base mult of 16)
  const int key = (lr >> 1) & 3;
  const int rsl = (sl ^ key) << 3;
  const int aoff = lr * 32 + rsl;                    // A rows 0..63 (all waves)
  const int boff = ABUF + (w * 64 + lr) * 32 + rsl;  // B rows w*64..w*64+63

  floatx4 acc[4][4] = {};
  short8 a[4], b[4];

#define STG(BP, T_) do { int kb_ = (T_) * 32; \
    gload_lds16(Asrc + (size_t)(tid >> 2) * K + sc * 8 + kb_, \
                (BP) + w * 512); \
    _Pragma("unroll") for (int it_ = 0; it_ < 4; ++it_) \
      gload_lds16(Bsrc + (size_t)((it_ * 256 + tid) >> 2) * K + sc * 8 + kb_, \
                  (BP) + ABUF + it_ * 2048 + w * 512); \
  } while (0)
#define LDAB(BP) do { \
    const u16* sa_ = (BP) + aoff; const u16* sb_ = (BP) + boff; \
    _Pragma("unroll") for (int i_ = 0; i_ < 4; ++i_) { \
      a[i_] = *reinterpret_cast<const short8*>(sa_ + i_ * 512); \
      b[i_] = *reinterpret_cast<const short8*>(sb_ + i_ * 512); } } while (0)
#define MMX() do { \
    _Pragma("unroll") for (int mf_ = 0; mf_ < 4; ++mf_) \
      _Pragma("unroll") for (int nf_ = 0; nf_ < 4; ++nf_) \
        acc[mf_][nf_] = __builtin_amdgcn_mfma_f32_16x16x32_bf16( \
            a[mf_], b[nf_], acc[mf_][nf_], 0, 0, 0); } while (0)

  STG(LD, 0);
  __syncthreads();
  #pragma unroll 1
  for (int t = 0; t < NT - 1; ++t) {
    u16* cur = LD + (t & 1) * BUF;
    u16* nxt = LD + ((t + 1) & 1) * BUF;
    STG(nxt, t + 1);
    LDAB(cur);
    MMX();
    __syncthreads();
  }
  LDAB(LD + ((NT - 1) & 1) * BUF);
  MMX();
  __syncthreads();

  // ---- epilogue (C/D: col=lane&15, row=(lane>>4)*4+i); rows 0..63 ----
  float b1v[4], wgv[4];
  #pragma unroll
  for (int nf = 0; nf < 4; ++nf) {
    int col = n0 + w * 64 + nf * 16 + lr;
    b1v[nf] = b1p[col];
    wgv[nf] = wgp[col];
  }
  float* red = (float*)LD;   // [4 waves][64 rows]
  #pragma unroll
  for (int mf = 0; mf < 4; ++mf)
    #pragma unroll
    for (int i2 = 0; i2 < 4; ++i2) {
      float p = 0.f;
      #pragma unroll
      for (int nf = 0; nf < 4; ++nf)
        p += fmaxf(acc[mf][nf][i2] + b1v[nf], 0.f) * wgv[nf];
      p += __shfl_xor(p, 1); p += __shfl_xor(p, 2);
      p += __shfl_xor(p, 4); p += __shfl_xor(p, 8);
      if (lr == 0) red[w * 64 + mf * 16 + sl * 4 + i2] = p;
    }
  __syncthreads();
  const int d = bx;
  const float cgv = cgp[d];
  float gv_[4][4];
  #pragma unroll
  for (int mf = 0; mf < 4; ++mf)
    #pragma unroll
    for (int i2 = 0; i2 < 4; ++i2) {
      int rl = mf * 16 + sl * 4 + i2;
      int r = m0 + rl;
      float logit = red[rl] + red[64 + rl] + red[128 + rl] + red[192 + rl]
                  + xu[(size_t)d * T_TOK + r] + cgv;
      float g = 1.f / (1.f + expf(-logit));
      gv_[mf][i2] = g;
      if (lr == 0 && w == 0) gateOut[(size_t)d * T_TOK + r] = g;
    }
  __syncthreads();
  // bounce tile [64][264] u16 at LD+512 elems (above red's 1KB)
  u16* tile = LD + 512;
  #pragma unroll
  for (int mf = 0; mf < 4; ++mf)
    #pragma unroll
    for (int i2 = 0; i2 < 4; ++i2) {
      int rl = mf * 16 + sl * 4 + i2;
      #pragma unroll
      for (int nf = 0; nf < 4; ++nf) {
        int cl = w * 64 + nf * 16 + lr;
        float v = fmaxf(acc[mf][nf][i2] + b1v[nf], 0.f);
        tile[rl * 264 + cl] = f2bf(v * gv_[mf][i2]);
      }
    }
  __syncthreads();
  #pragma unroll
  for (int it = 0; it < 8; ++it) {
    int q = it * 256 + tid;
    int row = q >> 5, ch = q & 31;
    short8 v = *reinterpret_cast<const short8*>(tile + row * 264 + ch * 8);
    *reinterpret_cast<short8*>(
        &o16[(size_t)(m0 + row) * DF + n0 + ch * 8]) = v;
  }
#undef STG
#undef LDAB
#undef MMX
}

// ------------- GEMM2 (R10-exact): m97 128x128xBK64, 3 blocks/CU -------------
__global__ __launch_bounds__(256, 3)
void gemm_g2(const u16* __restrict__ A, const u16* __restrict__ Bm,
             const float* __restrict__ x, const float* __restrict__ gate,
             const float* __restrict__ b2, float* __restrict__ outF)
{
  constexpr int K = DF, NT = K / 64;
  extern __shared__ u16 LD[];         // As @0 (8192), Bs @8192 (8192)

  const int tid = threadIdx.x, lane = tid & 63, w = tid >> 6;
  const int wm = w >> 1, wn = w & 1, lr = lane & 15, sl = lane >> 4;

  const int bid = blockIdx.x;
  const int xcd = bid & 7, idx = bid >> 3;
  const int by = xcd * 16 + idx / 8;
  const int bx = idx % 8;
  const int m0 = by * 128, n0 = bx * 128;

  const u16* Asrc = A + (size_t)m0 * K;
  const u16* Bsrc = Bm + (size_t)n0 * K;

  const int sc8 = ((tid & 7) ^ ((tid >> 3) & 7)) << 3;
  const int grow = tid >> 3;
  const int w512 = w * 512;
  const int rk = lr & 7;
  const int arow = (wm * 64 + lr) * 64;
  const int brow = 8192 + (wn * 64 + lr) * 64;

  floatx4 acc[4][4] = {};
  short8 a[4], b[4];

#define STG(kb_) do { \
    _Pragma("unroll") for (int it_ = 0; it_ < 4; ++it_) \
      gload_lds16(Asrc + (size_t)(it_ * 32 + grow) * K + sc8 + (kb_), \
                  LD + it_ * 2048 + w512); \
    _Pragma("unroll") for (int it_ = 0; it_ < 4; ++it_) \
      gload_lds16(Bsrc + (size_t)(it_ * 32 + grow) * K + sc8 + (kb_), \
                  LD + 8192 + it_ * 2048 + w512); \
  } while (0)
#define LDAB(ks) do { \
    const int ch_ = (((ks) * 4 + sl) ^ rk) << 3; \
    _Pragma("unroll") for (int i_ = 0; i_ < 4; ++i_) { \
      a[i_] = *reinterpret_cast<const short8*>(LD + arow + i_ * 1024 + ch_); \
      b[i_] = *reinterpret_cast<const short8*>(LD + brow + i_ * 1024 + ch_); } \
  } while (0)
#define MMX() do { \
    _Pragma("unroll") for (int mf_ = 0; mf_ < 4; ++mf_) \
      _Pragma("unroll") for (int nf_ = 0; nf_ < 4; ++nf_) \
        acc[mf_][nf_] = __builtin_amdgcn_mfma_f32_16x16x32_bf16( \
            a[mf_], b[nf_], acc[mf_][nf_], 0, 0, 0); } while (0)

  #pragma unroll 1
  for (int t = 0; t < NT; ++t) {
    STG(t * 64);
    __syncthreads();
    LDAB(0); MMX();
    LDAB(1); MMX();
    __syncthreads();
  }

  // epilogue: out = acc + 2x + sum_d g_d*b2_d (fp32 full sectors)
  float b2v[3][4];
  #pragma unroll
  for (int dd = 0; dd < 3; ++dd)
    #pragma unroll
    for (int nf = 0; nf < 4; ++nf)
      b2v[dd][nf] = b2[dd * H + n0 + wn * 64 + nf * 16 + lr];
  #pragma unroll
  for (int mf = 0; mf < 4; ++mf)
    #pragma unroll
    for (int i2 = 0; i2 < 4; ++i2) {
      int r = m0 + wm * 64 + mf * 16 + sl * 4 + i2;
      float g0 = gate[r], g1 = gate[T_TOK + r], g2 = gate[2 * T_TOK + r];
      const float* xrow = x + (size_t)r * H;
      float* orow = outF + (size_t)r * H;
      #pragma unroll
      for (int nf = 0; nf < 4; ++nf) {
        int col = n0 + wn * 64 + nf * 16 + lr;
        orow[col] = acc[mf][nf][i2] + 2.f * xrow[col]
                  + g0 * b2v[0][nf] + g1 * b2v[1][nf] + g2 * b2v[2][nf];
      }
    }
#undef STG
#undef LDAB
#undef MMX
}

// ---------------- launch ----------------

extern "C" void kernel_launch(void* const* d_in, const int* in_sizes, int n_in,
                              void* d_out, int out_size, void* d_ws, size_t ws_size,
                              hipStream_t stream) {
  const float* x   = (const float*)d_in[0];
  const float* lng = (const float*)d_in[1];
  const float* lnb = (const float*)d_in[2];
  const float* W1  = (const float*)d_in[3];
  const float* b1  = (const float*)d_in[4];
  const float* W2  = (const float*)d_in[5];
  const float* b2  = (const float*)d_in[6];
  const float* gu  = (const float*)d_in[7];
  const float* gv  = (const float*)d_in[8];
  const float* gb  = (const float*)d_in[9];
  float* out = (float*)d_out;

  char* ws = (char*)d_ws;
  u16* xn   = (u16*)ws;  ws += (size_t)T_TOK * H * 2;     // 32 MB
  u16* mid  = (u16*)ws;  ws += (size_t)T_TOK * DF * 2;    // 24 MB
  u16* W1p  = (u16*)ws;  ws += (size_t)DF * H * 2;
  u16* W2r  = (u16*)ws;  ws += (size_t)H * DF * 2;
  float* b1p  = (float*)ws;  ws += DF * 4;
  float* wg   = (float*)ws;  ws += DF * 4;
  float* cg   = (float*)ws;  ws += 256;
  float* xu   = (float*)ws;  ws += (size_t)D * T_TOK * 4;
  float* gate = (float*)ws;  ws += (size_t)D * T_TOK * 4;
  (void)ws_size; (void)in_sizes; (void)n_in; (void)out_size;

  hipFuncSetAttribute(reinterpret_cast<const void*>(&gemm_g1),
                      hipFuncAttributeMaxDynamicSharedMemorySize, 40960);
  hipFuncSetAttribute(reinterpret_cast<const void*>(&gemm_g2),
                      hipFuncAttributeMaxDynamicSharedMemorySize, 32768);

  // fused LN + weight prep (independent block families, one launch)
  prep_ln<<<T_TOK + DF, 256, 0, stream>>>(
      x, gu, W1, lng, lnb, b1, W2, gv, b2, gb,
      xn, xu, W1p, W2r, b1p, wg, cg);
  // GEMM1: mid = gate * relu(xn·W1p^T + b1p); BM=64, grid 768 = 3 rounds
  gemm_g1<<<256 * 3, 256, 40960, stream>>>(
      xn, W1p, b1p, wg, xu, cg, mid, gate);
  // GEMM2: out = midg·W2r^T + 2x + sum_d gate_d*b2_d
  gemm_g2<<<128 * 8, 256, 32768, stream>>>(
      mid, W2r, x, gate, b2, out);
}

// Round 17
// 122.220 us; speedup vs baseline: 1.0044x; 1.0044x over previous
//
#include <hip/hip_runtime.h>
#include <cstdint>

#define T_TOK 16384
#define H 1024
#define F 256
#define D 3
#define DF 768

typedef unsigned short u16;
typedef __attribute__((ext_vector_type(8))) short short8;
typedef __attribute__((ext_vector_type(4))) float floatx4;

__device__ __forceinline__ u16 f2bf(float f) {
  unsigned u = __float_as_uint(f);
  u += 0x7fff + ((u >> 16) & 1);   // round-to-nearest-even
  return (u16)(u >> 16);
}
__device__ __forceinline__ float bf2f(u16 s) {
  return __uint_as_float(((unsigned)s) << 16);
}

__device__ __forceinline__ void gload_lds16(const void* g, void* l) {
  __builtin_amdgcn_global_load_lds(
      reinterpret_cast<const __attribute__((address_space(1))) void*>(
          reinterpret_cast<uintptr_t>(g)),
      reinterpret_cast<__attribute__((address_space(3))) void*>(
          reinterpret_cast<uintptr_t>(l)),
      16, 0, 0);
}

__device__ __forceinline__ float block_reduce_256(float v, float* red, int tid) {
  #pragma unroll
  for (int o = 32; o > 0; o >>= 1) v += __shfl_xor(v, o);
  __syncthreads();
  if ((tid & 63) == 0) red[tid >> 6] = v;
  __syncthreads();
  return red[0] + red[1] + red[2] + red[3];
}

// -------- fused LN + prep: blocks [0,T_TOK) do LayerNorm+x·gu; blocks
// [T_TOK, T_TOK+DF) do the weight prep (dots + elementwise bf16 convert).
// Independent block families; prep hides under LN's BW-bound time.
__global__ __launch_bounds__(256)
void prep_ln(const float* __restrict__ x, const float* __restrict__ gu,
             const float* __restrict__ W1, const float* __restrict__ lng,
             const float* __restrict__ lnb, const float* __restrict__ b1,
             const float* __restrict__ W2, const float* __restrict__ gv,
             const float* __restrict__ b2, const float* __restrict__ gb,
             u16* __restrict__ xn, float* __restrict__ xu,
             u16* __restrict__ W1p, u16* __restrict__ W2r,
             float* __restrict__ b1p, float* __restrict__ wg,
             float* __restrict__ cg)
{
  const int tid = threadIdx.x;
  if (blockIdx.x < T_TOK) {
    // ---- LayerNorm + gate x-dots ----
    int t = blockIdx.x;
    const float4 xv = *reinterpret_cast<const float4*>(x + (size_t)t * H + tid * 4);
    const float4 g0 = *reinterpret_cast<const float4*>(gu + tid * 4);
    const float4 g1 = *reinterpret_cast<const float4*>(gu + H + tid * 4);
    const float4 g2 = *reinterpret_cast<const float4*>(gu + 2 * H + tid * 4);
    float s  = xv.x + xv.y + xv.z + xv.w;
    float sq = xv.x * xv.x + xv.y * xv.y + xv.z * xv.z + xv.w * xv.w;
    float d0 = xv.x * g0.x + xv.y * g0.y + xv.z * g0.z + xv.w * g0.w;
    float d1 = xv.x * g1.x + xv.y * g1.y + xv.z * g1.z + xv.w * g1.w;
    float d2 = xv.x * g2.x + xv.y * g2.y + xv.z * g2.z + xv.w * g2.w;
    #pragma unroll
    for (int o = 32; o > 0; o >>= 1) {
      s  += __shfl_xor(s, o);  sq += __shfl_xor(sq, o);
      d0 += __shfl_xor(d0, o); d1 += __shfl_xor(d1, o); d2 += __shfl_xor(d2, o);
    }
    __shared__ float red[4][5];
    int w = tid >> 6;
    if ((tid & 63) == 0) {
      red[w][0] = s; red[w][1] = sq; red[w][2] = d0; red[w][3] = d1; red[w][4] = d2;
    }
    __syncthreads();
    float S  = red[0][0] + red[1][0] + red[2][0] + red[3][0];
    float SQ = red[0][1] + red[1][1] + red[2][1] + red[3][1];
    float mu = S * (1.0f / H);
    float var = (SQ - (float)H * mu * mu) * (1.0f / (H - 1));
    float rs = 1.0f / (sqrtf(fmaxf(var, 0.0f)) + 1e-6f);
    ushort4 o4;
    o4.x = f2bf((xv.x - mu) * rs);
    o4.y = f2bf((xv.y - mu) * rs);
    o4.z = f2bf((xv.z - mu) * rs);
    o4.w = f2bf((xv.w - mu) * rs);
    *reinterpret_cast<ushort4*>(xn + (size_t)t * H + tid * 4) = o4;
    if (tid == 0) {
      xu[t]             = red[0][2] + red[1][2] + red[2][2] + red[3][2];
      xu[T_TOK + t]     = red[0][3] + red[1][3] + red[2][3] + red[3][3];
      xu[2 * T_TOK + t] = red[0][4] + red[1][4] + red[2][4] + red[3][4];
    }
  } else {
    // ---- weight prep: one block per (d,f) ----
    __shared__ float red[4];
    int pb = blockIdx.x - T_TOK;     // 0..DF-1
    int d = pb >> 8;
    int f = pb & 255;
    float s1 = 0.f, s2 = 0.f, s3 = 0.f;
    for (int h = tid; h < H; h += 256) {
      float w1v = W1[((size_t)d * F + f) * H + h];
      float gvv = gv[d * H + h];
      s1 += lnb[d * H + h] * w1v;
      s2 += W2[((size_t)d * H + h) * F + f] * gvv;
      if (f == 0) s3 += b2[d * H + h] * gvv;
    }
    float S1 = block_reduce_256(s1, red, tid);
    float S2 = block_reduce_256(s2, red, tid);
    if (tid == 0) {
      b1p[d * F + f] = b1[d * F + f] + S1;
      wg[d * F + f] = S2;
    }
    if (f == 0) {
      float S3 = block_reduce_256(s3, red, tid);
      if (tid == 0) cg[d] = gb[d] + S3;
    }
    // elementwise conversions (grid-stride over prep blocks only)
    int idx = pb * 256 + tid;
    int stride = DF * 256;
    for (int i = idx; i < D * F * H; i += stride) {
      int h = i & (H - 1);
      int dd = i / (F * H);
      W1p[i] = f2bf(W1[i] * lng[dd * H + h]);
    }
    for (int i = idx; i < H * DF; i += stride) {
      int k = i % DF;           // d*F+f
      int hh = i / DF;
      int dd = k >> 8;
      int ff = k & (F - 1);
      W2r[i] = f2bf(W2[((size_t)dd * H + hh) * F + ff]);
    }
  }
}

// ------------- GEMM1 (R16): 64x256xBK32, 4 waves of 64x64 -------------
// BM=64 -> grid 768 = 3 rounds @ 3 blocks/CU (R10 showed this regime is
// worth ~12% vs 1.5 rounds @ 2/CU). acc[4][4]=64 VGPR fits (256,3)'s
// ~170-reg cap with margin (NO acc[4][8] here — that tile spills at any
// 3-waves/EU bound: R8/R11/R14). 4 waves: all share A rows 0..63, wave w
// owns cols w*64..w*64+63. LDS 40KB dbuf (A 4KB + B 16KB per buffer),
// one __syncthreads per K-tile, compiler waits, chunk-XOR swizzle,
// panel dispatch. BN=256 == one domain -> gate fused in-block.
__global__ __launch_bounds__(256, 3)
void gemm_g1(const u16* __restrict__ A, const u16* __restrict__ Bm,
             const float* __restrict__ b1p, const float* __restrict__ wgp,
             const float* __restrict__ xu, const float* __restrict__ cgp,
             u16* __restrict__ o16, float* __restrict__ gateOut)
{
  constexpr int K = 1024, NT = K / 32;
  constexpr int ABUF = 2048;          // A slab u16 (64x32)
  constexpr int BUF = 10240;          // 20KB per buffer
  extern __shared__ u16 LD[];

  const int tid = threadIdx.x, lane = tid & 63, w = tid >> 6;
  const int lr = lane & 15, sl = lane >> 4;

  // panel dispatch: 256 by-tiles = 8 XCDs x 32; 3 bx per by consecutive
  const int bid = blockIdx.x;
  const int xcd = bid & 7, idx = bid >> 3;
  const int by = xcd * 32 + idx / 3;
  const int bx = idx % 3;
  const int m0 = by * 64, n0 = bx * 256;

  const u16* Asrc = A + (size_t)m0 * K;
  const u16* Bsrc = Bm + (size_t)n0 * K;

  // staging: chunk q (16B): row=q>>2, c=q&3; src chunk pre-swizzled
  // sc = c ^ ((row>>1)&3) = (tid&3)^((tid>>3)&3)  (it-invariant: +64 rows)
  const int sc = (tid & 3) ^ ((tid >> 3) & 3);
  // fragment reads: key = (lr>>1)&3 (row = base + lr, base mult of 16)
  const int key = (lr >> 1) & 3;
  const int rsl = (sl ^ key) << 3;
  const int aoff = lr * 32 + rsl;                    // A rows 0..63 (all waves)
  const int boff = ABUF + (w * 64 + lr) * 32 + rsl;  // B rows w*64..w*64+63

  floatx4 acc[4][4] = {};
  short8 a[4], b[4];

#define STG(BP, T_) do { int kb_ = (T_) * 32; \
    gload_lds16(Asrc + (size_t)(tid >> 2) * K + sc * 8 + kb_, \
                (BP) + w * 512); \
    _Pragma("unroll") for (int it_ = 0; it_ < 4; ++it_) \
      gload_lds16(Bsrc + (size_t)((it_ * 256 + tid) >> 2) * K + sc * 8 + kb_, \
                  (BP) + ABUF + it_ * 2048 + w * 512); \
  } while (0)
#define LDAB(BP) do { \
    const u16* sa_ = (BP) + aoff; const u16* sb_ = (BP) + boff; \
    _Pragma("unroll") for (int i_ = 0; i_ < 4; ++i_) { \
      a[i_] = *reinterpret_cast<const short8*>(sa_ + i_ * 512); \
      b[i_] = *reinterpret_cast<const short8*>(sb_ + i_ * 512); } } while (0)
#define MMX() do { \
    _Pragma("unroll") for (int mf_ = 0; mf_ < 4; ++mf_) \
      _Pragma("unroll") for (int nf_ = 0; nf_ < 4; ++nf_) \
        acc[mf_][nf_] = __builtin_amdgcn_mfma_f32_16x16x32_bf16( \
            a[mf_], b[nf_], acc[mf_][nf_], 0, 0, 0); } while (0)

  STG(LD, 0);
  __syncthreads();
  #pragma unroll 1
  for (int t = 0; t < NT - 1; ++t) {
    u16* cur = LD + (t & 1) * BUF;
    u16* nxt = LD + ((t + 1) & 1) * BUF;
    STG(nxt, t + 1);
    LDAB(cur);
    MMX();
    __syncthreads();
  }
  LDAB(LD + ((NT - 1) & 1) * BUF);
  MMX();
  __syncthreads();

  // ---- epilogue (C/D: col=lane&15, row=(lane>>4)*4+i); rows 0..63 ----
  float b1v[4], wgv[4];
  #pragma unroll
  for (int nf = 0; nf < 4; ++nf) {
    int col = n0 + w * 64 + nf * 16 + lr;
    b1v[nf] = b1p[col];
    wgv[nf] = wgp[col];
  }
  float* red = (float*)LD;   // [4 waves][64 rows]
  #pragma unroll
  for (int mf = 0; mf < 4; ++mf)
    #pragma unroll
    for (int i2 = 0; i2 < 4; ++i2) {
      float p = 0.f;
      #pragma unroll
      for (int nf = 0; nf < 4; ++nf)
        p += fmaxf(acc[mf][nf][i2] + b1v[nf], 0.f) * wgv[nf];
      p += __shfl_xor(p, 1); p += __shfl_xor(p, 2);
      p += __shfl_xor(p, 4); p += __shfl_xor(p, 8);
      if (lr == 0) red[w * 64 + mf * 16 + sl * 4 + i2] = p;
    }
  __syncthreads();
  const int d = bx;
  const float cgv = cgp[d];
  float gv_[4][4];
  #pragma unroll
  for (int mf = 0; mf < 4; ++mf)
    #pragma unroll
    for (int i2 = 0; i2 < 4; ++i2) {
      int rl = mf * 16 + sl * 4 + i2;
      int r = m0 + rl;
      float logit = red[rl] + red[64 + rl] + red[128 + rl] + red[192 + rl]
                  + xu[(size_t)d * T_TOK + r] + cgv;
      float g = 1.f / (1.f + expf(-logit));
      gv_[mf][i2] = g;
      if (lr == 0 && w == 0) gateOut[(size_t)d * T_TOK + r] = g;
    }
  __syncthreads();
  // bounce tile [64][264] u16 at LD+512 elems (above red's 1KB)
  u16* tile = LD + 512;
  #pragma unroll
  for (int mf = 0; mf < 4; ++mf)
    #pragma unroll
    for (int i2 = 0; i2 < 4; ++i2) {
      int rl = mf * 16 + sl * 4 + i2;
      #pragma unroll
      for (int nf = 0; nf < 4; ++nf) {
        int cl = w * 64 + nf * 16 + lr;
        float v = fmaxf(acc[mf][nf][i2] + b1v[nf], 0.f);
        tile[rl * 264 + cl] = f2bf(v * gv_[mf][i2]);
      }
    }
  __syncthreads();
  #pragma unroll
  for (int it = 0; it < 8; ++it) {
    int q = it * 256 + tid;
    int row = q >> 5, ch = q & 31;
    short8 v = *reinterpret_cast<const short8*>(tile + row * 264 + ch * 8);
    *reinterpret_cast<short8*>(
        &o16[(size_t)(m0 + row) * DF + n0 + ch * 8]) = v;
  }
#undef STG
#undef LDAB
#undef MMX
}

// ------------- GEMM2 (R10-exact): m97 128x128xBK64, 3 blocks/CU -------------
__global__ __launch_bounds__(256, 3)
void gemm_g2(const u16* __restrict__ A, const u16* __restrict__ Bm,
             const float* __restrict__ x, const float* __restrict__ gate,
             const float* __restrict__ b2, float* __restrict__ outF)
{
  constexpr int K = DF, NT = K / 64;
  extern __shared__ u16 LD[];         // As @0 (8192), Bs @8192 (8192)

  const int tid = threadIdx.x, lane = tid & 63, w = tid >> 6;
  const int wm = w >> 1, wn = w & 1, lr = lane & 15, sl = lane >> 4;

  const int bid = blockIdx.x;
  const int xcd = bid & 7, idx = bid >> 3;
  const int by = xcd * 16 + idx / 8;
  const int bx = idx % 8;
  const int m0 = by * 128, n0 = bx * 128;

  const u16* Asrc = A + (size_t)m0 * K;
  const u16* Bsrc = Bm + (size_t)n0 * K;

  const int sc8 = ((tid & 7) ^ ((tid >> 3) & 7)) << 3;
  const int grow = tid >> 3;
  const int w512 = w * 512;
  const int rk = lr & 7;
  const int arow = (wm * 64 + lr) * 64;
  const int brow = 8192 + (wn * 64 + lr) * 64;

  floatx4 acc[4][4] = {};
  short8 a[4], b[4];

#define STG(kb_) do { \
    _Pragma("unroll") for (int it_ = 0; it_ < 4; ++it_) \
      gload_lds16(Asrc + (size_t)(it_ * 32 + grow) * K + sc8 + (kb_), \
                  LD + it_ * 2048 + w512); \
    _Pragma("unroll") for (int it_ = 0; it_ < 4; ++it_) \
      gload_lds16(Bsrc + (size_t)(it_ * 32 + grow) * K + sc8 + (kb_), \
                  LD + 8192 + it_ * 2048 + w512); \
  } while (0)
#define LDAB(ks) do { \
    const int ch_ = (((ks) * 4 + sl) ^ rk) << 3; \
    _Pragma("unroll") for (int i_ = 0; i_ < 4; ++i_) { \
      a[i_] = *reinterpret_cast<const short8*>(LD + arow + i_ * 1024 + ch_); \
      b[i_] = *reinterpret_cast<const short8*>(LD + brow + i_ * 1024 + ch_); } \
  } while (0)
#define MMX() do { \
    _Pragma("unroll") for (int mf_ = 0; mf_ < 4; ++mf_) \
      _Pragma("unroll") for (int nf_ = 0; nf_ < 4; ++nf_) \
        acc[mf_][nf_] = __builtin_amdgcn_mfma_f32_16x16x32_bf16( \
            a[mf_], b[nf_], acc[mf_][nf_], 0, 0, 0); } while (0)

  #pragma unroll 1
  for (int t = 0; t < NT; ++t) {
    STG(t * 64);
    __syncthreads();
    LDAB(0); MMX();
    LDAB(1); MMX();
    __syncthreads();
  }

  // epilogue: out = acc + 2x + sum_d g_d*b2_d (fp32 full sectors)
  float b2v[3][4];
  #pragma unroll
  for (int dd = 0; dd < 3; ++dd)
    #pragma unroll
    for (int nf = 0; nf < 4; ++nf)
      b2v[dd][nf] = b2[dd * H + n0 + wn * 64 + nf * 16 + lr];
  #pragma unroll
  for (int mf = 0; mf < 4; ++mf)
    #pragma unroll
    for (int i2 = 0; i2 < 4; ++i2) {
      int r = m0 + wm * 64 + mf * 16 + sl * 4 + i2;
      float g0 = gate[r], g1 = gate[T_TOK + r], g2 = gate[2 * T_TOK + r];
      const float* xrow = x + (size_t)r * H;
      float* orow = outF + (size_t)r * H;
      #pragma unroll
      for (int nf = 0; nf < 4; ++nf) {
        int col = n0 + wn * 64 + nf * 16 + lr;
        orow[col] = acc[mf][nf][i2] + 2.f * xrow[col]
                  + g0 * b2v[0][nf] + g1 * b2v[1][nf] + g2 * b2v[2][nf];
      }
    }
#undef STG
#undef LDAB
#undef MMX
}

// ---------------- launch ----------------

extern "C" void kernel_launch(void* const* d_in, const int* in_sizes, int n_in,
                              void* d_out, int out_size, void* d_ws, size_t ws_size,
                              hipStream_t stream) {
  const float* x   = (const float*)d_in[0];
  const float* lng = (const float*)d_in[1];
  const float* lnb = (const float*)d_in[2];
  const float* W1  = (const float*)d_in[3];
  const float* b1  = (const float*)d_in[4];
  const float* W2  = (const float*)d_in[5];
  const float* b2  = (const float*)d_in[6];
  const float* gu  = (const float*)d_in[7];
  const float* gv  = (const float*)d_in[8];
  const float* gb  = (const float*)d_in[9];
  float* out = (float*)d_out;

  char* ws = (char*)d_ws;
  u16* xn   = (u16*)ws;  ws += (size_t)T_TOK * H * 2;     // 32 MB
  u16* mid  = (u16*)ws;  ws += (size_t)T_TOK * DF * 2;    // 24 MB
  u16* W1p  = (u16*)ws;  ws += (size_t)DF * H * 2;
  u16* W2r  = (u16*)ws;  ws += (size_t)H * DF * 2;
  float* b1p  = (float*)ws;  ws += DF * 4;
  float* wg   = (float*)ws;  ws += DF * 4;
  float* cg   = (float*)ws;  ws += 256;
  float* xu   = (float*)ws;  ws += (size_t)D * T_TOK * 4;
  float* gate = (float*)ws;  ws += (size_t)D * T_TOK * 4;
  (void)ws_size; (void)in_sizes; (void)n_in; (void)out_size;

  hipFuncSetAttribute(reinterpret_cast<const void*>(&gemm_g1),
                      hipFuncAttributeMaxDynamicSharedMemorySize, 40960);
  hipFuncSetAttribute(reinterpret_cast<const void*>(&gemm_g2),
                      hipFuncAttributeMaxDynamicSharedMemorySize, 32768);

  // fused LN + weight prep (independent block families, one launch)
  prep_ln<<<T_TOK + DF, 256, 0, stream>>>(
      x, gu, W1, lng, lnb, b1, W2, gv, b2, gb,
      xn, xu, W1p, W2r, b1p, wg, cg);
  // GEMM1: mid = gate * relu(xn·W1p^T + b1p); BM=64, grid 768 = 3 rounds
  gemm_g1<<<256 * 3, 256, 40960, stream>>>(
      xn, W1p, b1p, wg, xu, cg, mid, gate);
  // GEMM2: out = midg·W2r^T + 2x + sum_d gate_d*b2_d
  gemm_g2<<<128 * 8, 256, 32768, stream>>>(
      mid, W2r, x, gate, b2, out);
}

// Round 18
// 117.401 us; speedup vs baseline: 1.0456x; 1.0410x over previous
//
#include <hip/hip_runtime.h>
#include <cstdint>

#define T_TOK 16384
#define H 1024
#define F 256
#define D 3
#define DF 768

typedef unsigned short u16;
typedef __attribute__((ext_vector_type(8))) short short8;
typedef __attribute__((ext_vector_type(4))) float floatx4;

__device__ __forceinline__ u16 f2bf(float f) {
  unsigned u = __float_as_uint(f);
  u += 0x7fff + ((u >> 16) & 1);   // round-to-nearest-even
  return (u16)(u >> 16);
}
__device__ __forceinline__ float bf2f(u16 s) {
  return __uint_as_float(((unsigned)s) << 16);
}

__device__ __forceinline__ void gload_lds16(const void* g, void* l) {
  __builtin_amdgcn_global_load_lds(
      reinterpret_cast<const __attribute__((address_space(1))) void*>(
          reinterpret_cast<uintptr_t>(g)),
      reinterpret_cast<__attribute__((address_space(3))) void*>(
          reinterpret_cast<uintptr_t>(l)),
      16, 0, 0);
}

__device__ __forceinline__ float block_reduce_256(float v, float* red, int tid) {
  #pragma unroll
  for (int o = 32; o > 0; o >>= 1) v += __shfl_xor(v, o);
  __syncthreads();
  if ((tid & 63) == 0) red[tid >> 6] = v;
  __syncthreads();
  return red[0] + red[1] + red[2] + red[3];
}

// -------- fused LN + prep: blocks [0,T_TOK) do LayerNorm+x·gu; blocks
// [T_TOK, T_TOK+DF) do the weight prep (dots + elementwise bf16 convert).
// Independent block families; prep hides under LN's BW-bound time.
__global__ __launch_bounds__(256)
void prep_ln(const float* __restrict__ x, const float* __restrict__ gu,
             const float* __restrict__ W1, const float* __restrict__ lng,
             const float* __restrict__ lnb, const float* __restrict__ b1,
             const float* __restrict__ W2, const float* __restrict__ gv,
             const float* __restrict__ b2, const float* __restrict__ gb,
             u16* __restrict__ xn, float* __restrict__ xu,
             u16* __restrict__ W1p, u16* __restrict__ W2r,
             float* __restrict__ b1p, float* __restrict__ wg,
             float* __restrict__ cg)
{
  const int tid = threadIdx.x;
  if (blockIdx.x < T_TOK) {
    // ---- LayerNorm + gate x-dots ----
    int t = blockIdx.x;
    const float4 xv = *reinterpret_cast<const float4*>(x + (size_t)t * H + tid * 4);
    const float4 g0 = *reinterpret_cast<const float4*>(gu + tid * 4);
    const float4 g1 = *reinterpret_cast<const float4*>(gu + H + tid * 4);
    const float4 g2 = *reinterpret_cast<const float4*>(gu + 2 * H + tid * 4);
    float s  = xv.x + xv.y + xv.z + xv.w;
    float sq = xv.x * xv.x + xv.y * xv.y + xv.z * xv.z + xv.w * xv.w;
    float d0 = xv.x * g0.x + xv.y * g0.y + xv.z * g0.z + xv.w * g0.w;
    float d1 = xv.x * g1.x + xv.y * g1.y + xv.z * g1.z + xv.w * g1.w;
    float d2 = xv.x * g2.x + xv.y * g2.y + xv.z * g2.z + xv.w * g2.w;
    #pragma unroll
    for (int o = 32; o > 0; o >>= 1) {
      s  += __shfl_xor(s, o);  sq += __shfl_xor(sq, o);
      d0 += __shfl_xor(d0, o); d1 += __shfl_xor(d1, o); d2 += __shfl_xor(d2, o);
    }
    __shared__ float red[4][5];
    int w = tid >> 6;
    if ((tid & 63) == 0) {
      red[w][0] = s; red[w][1] = sq; red[w][2] = d0; red[w][3] = d1; red[w][4] = d2;
    }
    __syncthreads();
    float S  = red[0][0] + red[1][0] + red[2][0] + red[3][0];
    float SQ = red[0][1] + red[1][1] + red[2][1] + red[3][1];
    float mu = S * (1.0f / H);
    float var = (SQ - (float)H * mu * mu) * (1.0f / (H - 1));
    float rs = 1.0f / (sqrtf(fmaxf(var, 0.0f)) + 1e-6f);
    ushort4 o4;
    o4.x = f2bf((xv.x - mu) * rs);
    o4.y = f2bf((xv.y - mu) * rs);
    o4.z = f2bf((xv.z - mu) * rs);
    o4.w = f2bf((xv.w - mu) * rs);
    *reinterpret_cast<ushort4*>(xn + (size_t)t * H + tid * 4) = o4;
    if (tid == 0) {
      xu[t]             = red[0][2] + red[1][2] + red[2][2] + red[3][2];
      xu[T_TOK + t]     = red[0][3] + red[1][3] + red[2][3] + red[3][3];
      xu[2 * T_TOK + t] = red[0][4] + red[1][4] + red[2][4] + red[3][4];
    }
  } else {
    // ---- weight prep: one block per (d,f) ----
    __shared__ float red[4];
    int pb = blockIdx.x - T_TOK;     // 0..DF-1
    int d = pb >> 8;
    int f = pb & 255;
    float s1 = 0.f, s2 = 0.f, s3 = 0.f;
    for (int h = tid; h < H; h += 256) {
      float w1v = W1[((size_t)d * F + f) * H + h];
      float gvv = gv[d * H + h];
      s1 += lnb[d * H + h] * w1v;
      s2 += W2[((size_t)d * H + h) * F + f] * gvv;
      if (f == 0) s3 += b2[d * H + h] * gvv;
    }
    float S1 = block_reduce_256(s1, red, tid);
    float S2 = block_reduce_256(s2, red, tid);
    if (tid == 0) {
      b1p[d * F + f] = b1[d * F + f] + S1;
      wg[d * F + f] = S2;
    }
    if (f == 0) {
      float S3 = block_reduce_256(s3, red, tid);
      if (tid == 0) cg[d] = gb[d] + S3;
    }
    // elementwise conversions (grid-stride over prep blocks only)
    int idx = pb * 256 + tid;
    int stride = DF * 256;
    for (int i = idx; i < D * F * H; i += stride) {
      int h = i & (H - 1);
      int dd = i / (F * H);
      W1p[i] = f2bf(W1[i] * lng[dd * H + h]);
    }
    for (int i = idx; i < H * DF; i += stride) {
      int k = i % DF;           // d*F+f
      int hh = i / DF;
      int dd = k >> 8;
      int ff = k & (F - 1);
      W2r[i] = f2bf(W2[((size_t)dd * H + hh) * F + ff]);
    }
  }
}

// ------------- GEMM1 (R13-exact): 128x256xBK32, 64x128 wave tile -------------
// __launch_bounds__(512,2): 256-reg cap — REQUIRED for the acc[4][8] wave
// tile (any 3-waves/EU bound spills it: R8/R11/R14 all lost 30-45us).
// 256 thr, 4 waves (2m x 2n), dbuf 48KB, one __syncthreads per K-tile,
// compiler waits, both-sides chunk-XOR swizzle, panel dispatch.
// BN=256 == one domain -> gate computed in-block.
__global__ __launch_bounds__(512, 2)
void gemm_g1(const u16* __restrict__ A, const u16* __restrict__ Bm,
             const float* __restrict__ b1p, const float* __restrict__ wgp,
             const float* __restrict__ xu, const float* __restrict__ cgp,
             u16* __restrict__ o16, float* __restrict__ gateOut)
{
  constexpr int K = 1024, NT = K / 32;
  constexpr int ABUF = 4096;          // A slab u16 (128x32)
  constexpr int BUF = 12288;          // 24KB per buffer
  extern __shared__ u16 LD[];

  const int tid = threadIdx.x, lane = tid & 63, w = tid >> 6;
  const int wm = w >> 1, wn = w & 1, lr = lane & 15, sl = lane >> 4;

  const int bid = blockIdx.x;
  const int xcd = bid & 7, idx = bid >> 3;
  const int by = xcd * 16 + idx / 3;
  const int bx = idx % 3;
  const int m0 = by * 128, n0 = bx * 256;

  const u16* Asrc = A + (size_t)m0 * K;
  const u16* Bsrc = Bm + (size_t)n0 * K;

  const int sc = (tid & 3) ^ ((tid >> 3) & 3);
  const int key = (lr >> 1) & 3;
  const int rsl = (sl ^ key) << 3;
  const int aoff = (wm * 64 + lr) * 32 + rsl;
  const int boff = ABUF + (wn * 128 + lr) * 32 + rsl;

  floatx4 acc[4][8] = {};
  short8 a[4], b[8];

#define STG(BP, T_) do { int kb_ = (T_) * 32; \
    _Pragma("unroll") for (int it_ = 0; it_ < 2; ++it_) \
      gload_lds16(Asrc + (size_t)((it_ * 256 + tid) >> 2) * K + sc * 8 + kb_, \
                  (BP) + it_ * 2048 + w * 512); \
    _Pragma("unroll") for (int it_ = 0; it_ < 4; ++it_) \
      gload_lds16(Bsrc + (size_t)((it_ * 256 + tid) >> 2) * K + sc * 8 + kb_, \
                  (BP) + ABUF + it_ * 2048 + w * 512); \
  } while (0)
#define LDAB(BP) do { \
    const u16* sa_ = (BP) + aoff; const u16* sb_ = (BP) + boff; \
    _Pragma("unroll") for (int i_ = 0; i_ < 4; ++i_) \
      a[i_] = *reinterpret_cast<const short8*>(sa_ + i_ * 512); \
    _Pragma("unroll") for (int j_ = 0; j_ < 8; ++j_) \
      b[j_] = *reinterpret_cast<const short8*>(sb_ + j_ * 512); } while (0)
#define MMX() do { \
    _Pragma("unroll") for (int mf_ = 0; mf_ < 4; ++mf_) \
      _Pragma("unroll") for (int nf_ = 0; nf_ < 8; ++nf_) \
        acc[mf_][nf_] = __builtin_amdgcn_mfma_f32_16x16x32_bf16( \
            a[mf_], b[nf_], acc[mf_][nf_], 0, 0, 0); } while (0)

  STG(LD, 0);
  __syncthreads();
  #pragma unroll 1
  for (int t = 0; t < NT - 1; ++t) {
    u16* cur = LD + (t & 1) * BUF;
    u16* nxt = LD + ((t + 1) & 1) * BUF;
    STG(nxt, t + 1);
    LDAB(cur);
    MMX();
    __syncthreads();
  }
  LDAB(LD + ((NT - 1) & 1) * BUF);
  MMX();
  __syncthreads();

  // epilogue (C/D: col=lane&15, row=(lane>>4)*4+i)
  float b1v[8], wgv[8];
  #pragma unroll
  for (int nf = 0; nf < 8; ++nf) {
    int col = n0 + wn * 128 + nf * 16 + lr;
    b1v[nf] = b1p[col];
    wgv[nf] = wgp[col];
  }
  float* red = (float*)LD;   // [2 wn][128 rows]
  #pragma unroll
  for (int mf = 0; mf < 4; ++mf)
    #pragma unroll
    for (int i2 = 0; i2 < 4; ++i2) {
      float p = 0.f;
      #pragma unroll
      for (int nf = 0; nf < 8; ++nf)
        p += fmaxf(acc[mf][nf][i2] + b1v[nf], 0.f) * wgv[nf];
      p += __shfl_xor(p, 1); p += __shfl_xor(p, 2);
      p += __shfl_xor(p, 4); p += __shfl_xor(p, 8);
      if (lr == 0) red[wn * 128 + wm * 64 + mf * 16 + sl * 4 + i2] = p;
    }
  __syncthreads();
  const int d = bx;
  const float cgv = cgp[d];
  float gv_[4][4];
  #pragma unroll
  for (int mf = 0; mf < 4; ++mf)
    #pragma unroll
    for (int i2 = 0; i2 < 4; ++i2) {
      int rl = wm * 64 + mf * 16 + sl * 4 + i2;
      int r = m0 + rl;
      float logit = red[rl] + red[128 + rl] + xu[(size_t)d * T_TOK + r] + cgv;
      float g = 1.f / (1.f + expf(-logit));
      gv_[mf][i2] = g;
      if (lr == 0 && wn == 0) gateOut[(size_t)d * T_TOK + r] = g;
    }
  __syncthreads();
  u16* tile = LD + 512;      // [64][264] bounce above red
  #pragma unroll
  for (int ph = 0; ph < 2; ++ph) {
    if (wm == ph) {
      #pragma unroll
      for (int mf = 0; mf < 4; ++mf)
        #pragma unroll
        for (int i2 = 0; i2 < 4; ++i2) {
          int rl = mf * 16 + sl * 4 + i2;
          #pragma unroll
          for (int nf = 0; nf < 8; ++nf) {
            int cl = wn * 128 + nf * 16 + lr;
            float v = fmaxf(acc[mf][nf][i2] + b1v[nf], 0.f);
            tile[rl * 264 + cl] = f2bf(v * gv_[mf][i2]);
          }
        }
    }
    __syncthreads();
    #pragma unroll
    for (int it = 0; it < 8; ++it) {
      int q = it * 256 + tid;
      int row = q >> 5, ch = q & 31;
      short8 v = *reinterpret_cast<const short8*>(tile + row * 264 + ch * 8);
      *reinterpret_cast<short8*>(
          &o16[(size_t)(m0 + ph * 64 + row) * DF + n0 + ch * 8]) = v;
    }
    __syncthreads();
  }
#undef STG
#undef LDAB
#undef MMX
}

// ------------- GEMM2 (R10-exact): m97 128x128xBK64, 3 blocks/CU -------------
__global__ __launch_bounds__(256, 3)
void gemm_g2(const u16* __restrict__ A, const u16* __restrict__ Bm,
             const float* __restrict__ x, const float* __restrict__ gate,
             const float* __restrict__ b2, float* __restrict__ outF)
{
  constexpr int K = DF, NT = K / 64;
  extern __shared__ u16 LD[];         // As @0 (8192), Bs @8192 (8192)

  const int tid = threadIdx.x, lane = tid & 63, w = tid >> 6;
  const int wm = w >> 1, wn = w & 1, lr = lane & 15, sl = lane >> 4;

  const int bid = blockIdx.x;
  const int xcd = bid & 7, idx = bid >> 3;
  const int by = xcd * 16 + idx / 8;
  const int bx = idx % 8;
  const int m0 = by * 128, n0 = bx * 128;

  const u16* Asrc = A + (size_t)m0 * K;
  const u16* Bsrc = Bm + (size_t)n0 * K;

  const int sc8 = ((tid & 7) ^ ((tid >> 3) & 7)) << 3;
  const int grow = tid >> 3;
  const int w512 = w * 512;
  const int rk = lr & 7;
  const int arow = (wm * 64 + lr) * 64;
  const int brow = 8192 + (wn * 64 + lr) * 64;

  floatx4 acc[4][4] = {};
  short8 a[4], b[4];

#define STG(kb_) do { \
    _Pragma("unroll") for (int it_ = 0; it_ < 4; ++it_) \
      gload_lds16(Asrc + (size_t)(it_ * 32 + grow) * K + sc8 + (kb_), \
                  LD + it_ * 2048 + w512); \
    _Pragma("unroll") for (int it_ = 0; it_ < 4; ++it_) \
      gload_lds16(Bsrc + (size_t)(it_ * 32 + grow) * K + sc8 + (kb_), \
                  LD + 8192 + it_ * 2048 + w512); \
  } while (0)
#define LDAB(ks) do { \
    const int ch_ = (((ks) * 4 + sl) ^ rk) << 3; \
    _Pragma("unroll") for (int i_ = 0; i_ < 4; ++i_) { \
      a[i_] = *reinterpret_cast<const short8*>(LD + arow + i_ * 1024 + ch_); \
      b[i_] = *reinterpret_cast<const short8*>(LD + brow + i_ * 1024 + ch_); } \
  } while (0)
#define MMX() do { \
    _Pragma("unroll") for (int mf_ = 0; mf_ < 4; ++mf_) \
      _Pragma("unroll") for (int nf_ = 0; nf_ < 4; ++nf_) \
        acc[mf_][nf_] = __builtin_amdgcn_mfma_f32_16x16x32_bf16( \
            a[mf_], b[nf_], acc[mf_][nf_], 0, 0, 0); } while (0)

  #pragma unroll 1
  for (int t = 0; t < NT; ++t) {
    STG(t * 64);
    __syncthreads();
    LDAB(0); MMX();
    LDAB(1); MMX();
    __syncthreads();
  }

  // epilogue: out = acc + 2x + sum_d g_d*b2_d (fp32 full sectors)
  float b2v[3][4];
  #pragma unroll
  for (int dd = 0; dd < 3; ++dd)
    #pragma unroll
    for (int nf = 0; nf < 4; ++nf)
      b2v[dd][nf] = b2[dd * H + n0 + wn * 64 + nf * 16 + lr];
  #pragma unroll
  for (int mf = 0; mf < 4; ++mf)
    #pragma unroll
    for (int i2 = 0; i2 < 4; ++i2) {
      int r = m0 + wm * 64 + mf * 16 + sl * 4 + i2;
      float g0 = gate[r], g1 = gate[T_TOK + r], g2 = gate[2 * T_TOK + r];
      const float* xrow = x + (size_t)r * H;
      float* orow = outF + (size_t)r * H;
      #pragma unroll
      for (int nf = 0; nf < 4; ++nf) {
        int col = n0 + wn * 64 + nf * 16 + lr;
        orow[col] = acc[mf][nf][i2] + 2.f * xrow[col]
                  + g0 * b2v[0][nf] + g1 * b2v[1][nf] + g2 * b2v[2][nf];
      }
    }
#undef STG
#undef LDAB
#undef MMX
}

// ---------------- launch ----------------

extern "C" void kernel_launch(void* const* d_in, const int* in_sizes, int n_in,
                              void* d_out, int out_size, void* d_ws, size_t ws_size,
                              hipStream_t stream) {
  const float* x   = (const float*)d_in[0];
  const float* lng = (const float*)d_in[1];
  const float* lnb = (const float*)d_in[2];
  const float* W1  = (const float*)d_in[3];
  const float* b1  = (const float*)d_in[4];
  const float* W2  = (const float*)d_in[5];
  const float* b2  = (const float*)d_in[6];
  const float* gu  = (const float*)d_in[7];
  const float* gv  = (const float*)d_in[8];
  const float* gb  = (const float*)d_in[9];
  float* out = (float*)d_out;

  char* ws = (char*)d_ws;
  u16* xn   = (u16*)ws;  ws += (size_t)T_TOK * H * 2;     // 32 MB
  u16* mid  = (u16*)ws;  ws += (size_t)T_TOK * DF * 2;    // 24 MB
  u16* W1p  = (u16*)ws;  ws += (size_t)DF * H * 2;
  u16* W2r  = (u16*)ws;  ws += (size_t)H * DF * 2;
  float* b1p  = (float*)ws;  ws += DF * 4;
  float* wg   = (float*)ws;  ws += DF * 4;
  float* cg   = (float*)ws;  ws += 256;
  float* xu   = (float*)ws;  ws += (size_t)D * T_TOK * 4;
  float* gate = (float*)ws;  ws += (size_t)D * T_TOK * 4;
  (void)ws_size; (void)in_sizes; (void)n_in; (void)out_size;

  hipFuncSetAttribute(reinterpret_cast<const void*>(&gemm_g1),
                      hipFuncAttributeMaxDynamicSharedMemorySize, 49152);
  hipFuncSetAttribute(reinterpret_cast<const void*>(&gemm_g2),
                      hipFuncAttributeMaxDynamicSharedMemorySize, 32768);

  // fused LN + weight prep (independent block families, one launch)
  prep_ln<<<T_TOK + DF, 256, 0, stream>>>(
      x, gu, W1, lng, lnb, b1, W2, gv, b2, gb,
      xn, xu, W1p, W2r, b1p, wg, cg);
  // GEMM1: mid = gate * relu(xn·W1p^T + b1p); gate fused (BN=256=domain)
  gemm_g1<<<128 * 3, 256, 49152, stream>>>(
      xn, W1p, b1p, wg, xu, cg, mid, gate);
  // GEMM2: out = midg·W2r^T + 2x + sum_d gate_d*b2_d
  gemm_g2<<<128 * 8, 256, 32768, stream>>>(
      mid, W2r, x, gate, b2, out);
}